// Round 5
// baseline (400.812 us; speedup 1.0000x reference)
//
#include <hip/hip_runtime.h>

// ChannelAttention b=2, n=4096, c=32 fp32.
// S = X X^T (Gram), softmax over j per row i, out[j,c] = sum_i attn[i,j] x[i,c]; out*g + x.
//
// R4 diagnostic: per-rep pipeline = 41 us, of which ~30 us is 3x dispatch
// overhead (fixed harness floor = 53.5 us). R5: fuse all three phases into
// ONE dispatch with device-scope spin barriers.
//   phase0: convert x -> xf (f16 row-major) + xt (f16 transposed)   [blocks 0..127]
//   phase1: Z_i = sum_j exp(s_ij - 48) -> c2[i] = -(log(Z)+48)      [block = 16-i tile]
//   phase2: per 16-j tile: S-MFMA -> exp2 -> LDS C->A relayout -> PV-MFMA
// Residency proof for the spin barrier: __launch_bounds__(512,4) caps VGPR at
// 128 -> 4 waves/SIMD -> 2 blocks/CU (8-wave blocks); LDS 37KB*2 <= 160KB;
// grid = 512 = 2*256 -> ALL blocks resident. Flags in d_ws are re-poisoned to
// 0xAAAAAAAA (<0) before every launch, so "flag < epoch" with epochs 1,2 is
// correct and self-resetting across graph replays.

typedef _Float16 half8 __attribute__((ext_vector_type(8)));
typedef _Float16 half4v __attribute__((ext_vector_type(4)));
typedef float float4v __attribute__((ext_vector_type(4)));

#define NN 4096
#define CC 32
#define L2E 1.44269504f
#define SHIFT 48.0f
#define NBLK 512

__device__ __forceinline__ void gbar(int* __restrict__ flags, int epoch) {
    __syncthreads();
    __threadfence();   // device-scope release of this block's prior writes
    if (threadIdx.x == 0)
        __hip_atomic_store(&flags[blockIdx.x], epoch, __ATOMIC_RELEASE,
                           __HIP_MEMORY_SCOPE_AGENT);
    // 512 threads, 512 flags: one each
    while (__hip_atomic_load(&flags[threadIdx.x], __ATOMIC_ACQUIRE,
                             __HIP_MEMORY_SCOPE_AGENT) < epoch)
        __builtin_amdgcn_s_sleep(1);
    __syncthreads();
}

__global__ __launch_bounds__(512, 4) void k_fused(const float* __restrict__ x,
                                                  _Float16* __restrict__ xf,
                                                  _Float16* __restrict__ xt,
                                                  float* __restrict__ c2,
                                                  int* __restrict__ flags,
                                                  const float* __restrict__ gamma,
                                                  float* __restrict__ out) {
    const int tid = threadIdx.x;
    const int bid = blockIdx.x;
    const int wave = tid >> 6, lane = tid & 63;
    const int quad = lane >> 4, l15 = lane & 15;

    __shared__ float zw[8][16];
    __shared__ _Float16 pt[8][2][16 * 40];   // wave x parity x (16 rows, stride 40)
    __shared__ float red[8][16][32];

    // ---------------- phase 0: convert (blocks 0..127, 65536 threads) ----------------
    if (bid < 128) {
        const int t = bid * 512 + tid;
        const int n  = t & 4095;
        const int cg = (t >> 12) & 7;
        const int b  = t >> 15;
        const int row = (b << 12) | n;
        float4 v = *(const float4*)(x + (size_t)row * CC + cg * 4);
        _Float16 h0 = (_Float16)v.x, h1 = (_Float16)v.y, h2 = (_Float16)v.z, h3 = (_Float16)v.w;
        *(half4v*)(xf + (size_t)row * CC + cg * 4) = (half4v){h0, h1, h2, h3};
        _Float16* xtb = xt + (size_t)b * CC * NN;
        xtb[(cg * 4 + 0) * NN + n] = h0;   // consecutive lanes -> consecutive n
        xtb[(cg * 4 + 1) * NN + n] = h1;
        xtb[(cg * 4 + 2) * NN + n] = h2;
        xtb[(cg * 4 + 3) * NN + n] = h3;
    }

    gbar(flags, 1);

    // ---------------- phase 1: per-row shifted sum-of-exp -> c2 ----------------
    {
        const int b  = bid >> 8;
        const int i0 = (bid & 255) * 16;
        const _Float16* xb = xf + (size_t)b * NN * CC;

        const half8 afrag = *(const half8*)(xb + (size_t)(i0 + l15) * CC + quad * 8);
        const float4v zf = {0.f, 0.f, 0.f, 0.f};
        float z[4] = {0.f, 0.f, 0.f, 0.f};
        const float c2c = -SHIFT * L2E;

        const int jbase = wave * 512;
        for (int jt = 0; jt < 8; ++jt) {     // 8 iters x 4 tiles x 16 j = 512 j
            const int j0 = jbase + jt * 64;
            half8 b0 = *(const half8*)(xb + (size_t)(j0 + l15) * CC + quad * 8);
            half8 b1 = *(const half8*)(xb + (size_t)(j0 + 16 + l15) * CC + quad * 8);
            half8 b2 = *(const half8*)(xb + (size_t)(j0 + 32 + l15) * CC + quad * 8);
            half8 b3 = *(const half8*)(xb + (size_t)(j0 + 48 + l15) * CC + quad * 8);
            float4v s0 = __builtin_amdgcn_mfma_f32_16x16x32_f16(afrag, b0, zf, 0, 0, 0);
            float4v s1 = __builtin_amdgcn_mfma_f32_16x16x32_f16(afrag, b1, zf, 0, 0, 0);
            float4v s2 = __builtin_amdgcn_mfma_f32_16x16x32_f16(afrag, b2, zf, 0, 0, 0);
            float4v s3 = __builtin_amdgcn_mfma_f32_16x16x32_f16(afrag, b3, zf, 0, 0, 0);
#pragma unroll
            for (int r = 0; r < 4; ++r) {
                z[r] += __builtin_amdgcn_exp2f(fmaf(s0[r], L2E, c2c));
                z[r] += __builtin_amdgcn_exp2f(fmaf(s1[r], L2E, c2c));
                z[r] += __builtin_amdgcn_exp2f(fmaf(s2[r], L2E, c2c));
                z[r] += __builtin_amdgcn_exp2f(fmaf(s3[r], L2E, c2c));
            }
        }
#pragma unroll
        for (int off = 1; off <= 8; off <<= 1) {
#pragma unroll
            for (int r = 0; r < 4; ++r) z[r] += __shfl_xor(z[r], off, 64);
        }
        if (l15 == 0) {
#pragma unroll
            for (int r = 0; r < 4; ++r) zw[wave][quad * 4 + r] = z[r];
        }
        __syncthreads();
        if (tid < 16) {
            float zs = 0.f;
#pragma unroll
            for (int w = 0; w < 8; ++w) zs += zw[w][tid];
            c2[b * NN + i0 + tid] = -(__builtin_amdgcn_logf(zs) + SHIFT * L2E);
        }
    }

    gbar(flags, 2);

    // ---------------- phase 2: output pass ----------------
    {
        const int b  = bid >> 8;
        const int j0 = (bid & 255) * 16;
        const _Float16* xb  = xf + (size_t)b * NN * CC;
        const _Float16* xtb = xt + (size_t)b * CC * NN;
        const float* c2b = c2 + b * NN;

        const half8 bjfrag = *(const half8*)(xb + (size_t)(j0 + l15) * CC + quad * 8);
        const float4v zf = {0.f, 0.f, 0.f, 0.f};
        float4v acc0 = zf, acc1 = zf;

        const int ibase = wave * 512;
        half8 a0  = *(const half8*)(xb + (size_t)(ibase + l15) * CC + quad * 8);
        half8 a1  = *(const half8*)(xb + (size_t)(ibase + 16 + l15) * CC + quad * 8);
        half8 xb0 = *(const half8*)(xtb + (size_t)l15 * NN + ibase + quad * 8);
        half8 xb1 = *(const half8*)(xtb + (size_t)(l15 + 16) * NN + ibase + quad * 8);
        float4v c20 = *(const float4v*)(c2b + ibase + quad * 4);
        float4v c21 = *(const float4v*)(c2b + ibase + 16 + quad * 4);

        for (int it = 0; it < 16; ++it) {
            const int inx = ibase + ((it + 1) & 15) * 32;
            half8 na0  = *(const half8*)(xb + (size_t)(inx + l15) * CC + quad * 8);
            half8 na1  = *(const half8*)(xb + (size_t)(inx + 16 + l15) * CC + quad * 8);
            half8 nxb0 = *(const half8*)(xtb + (size_t)l15 * NN + inx + quad * 8);
            half8 nxb1 = *(const half8*)(xtb + (size_t)(l15 + 16) * NN + inx + quad * 8);
            float4v nc20 = *(const float4v*)(c2b + inx + quad * 4);
            float4v nc21 = *(const float4v*)(c2b + inx + 16 + quad * 4);

            float4v s0 = __builtin_amdgcn_mfma_f32_16x16x32_f16(a0, bjfrag, zf, 0, 0, 0);
            float4v s1 = __builtin_amdgcn_mfma_f32_16x16x32_f16(a1, bjfrag, zf, 0, 0, 0);
            half4v p0, p1;
#pragma unroll
            for (int r = 0; r < 4; ++r) {
                p0[r] = (_Float16)__builtin_amdgcn_exp2f(fmaf(s0[r], L2E, c20[r]));
                p1[r] = (_Float16)__builtin_amdgcn_exp2f(fmaf(s1[r], L2E, c21[r]));
            }
            _Float16* ptw = &pt[wave][it & 1][0];
            *(half4v*)(ptw + l15 * 40 + quad * 4)      = p0;
            *(half4v*)(ptw + l15 * 40 + 16 + quad * 4) = p1;
            half8 a2 = *(const half8*)(ptw + l15 * 40 + quad * 8);   // P^T[j=l15][i]
            acc0 = __builtin_amdgcn_mfma_f32_16x16x32_f16(a2, xb0, acc0, 0, 0, 0);
            acc1 = __builtin_amdgcn_mfma_f32_16x16x32_f16(a2, xb1, acc1, 0, 0, 0);

            a0 = na0; a1 = na1; xb0 = nxb0; xb1 = nxb1; c20 = nc20; c21 = nc21;
        }

#pragma unroll
        for (int r = 0; r < 4; ++r) {
            red[wave][quad * 4 + r][l15]      = acc0[r];
            red[wave][quad * 4 + r][l15 + 16] = acc1[r];
        }
        __syncthreads();
        {
            const int jj = tid >> 5, c = tid & 31;   // 512 threads = 16 j x 32 c
            float s = 0.f;
#pragma unroll
            for (int w = 0; w < 8; ++w) s += red[w][jj][c];
            const float g = gamma[0];
            const size_t o = (size_t)(b * NN + j0 + jj) * CC + c;
            out[o] = fmaf(g, s, x[o]);
        }
    }
}

extern "C" void kernel_launch(void* const* d_in, const int* in_sizes, int n_in,
                              void* d_out, int out_size, void* d_ws, size_t ws_size,
                              hipStream_t stream) {
    const float* x     = (const float*)d_in[0];
    const float* gamma = (const float*)d_in[1];
    float* out = (float*)d_out;

    // ws layout: xf f16 (512 KB) | xt f16 (512 KB) | c2 fp32 (32 KB) | flags (2 KB)
    _Float16* xf = (_Float16*)d_ws;
    _Float16* xt = xf + (size_t)2 * NN * CC;
    float*    c2 = (float*)(xt + (size_t)2 * CC * NN);
    int*   flags = (int*)(c2 + 2 * NN);

    k_fused<<<dim3(NBLK), dim3(512), 0, stream>>>(x, xf, xt, c2, flags, gamma, out);
}

// Round 6
// 238.284 us; speedup vs baseline: 1.6821x; 1.6821x over previous
//
#include <hip/hip_runtime.h>

// ChannelAttention b=2, n=4096, c=32 fp32.
// S = X X^T (Gram), softmax over j per row i, out[j,c] = sum_i attn[i,j] x[i,c]; out*g + x.
//
// Single fused dispatch, two device-wide barriers.
// R5 post-mortem: per-thread ACQUIRE-polling barrier = buffer_inv storm
// (358 us, WRITE_SIZE 19 MB). R6: lean barrier — tid0-only arrival via
// RELEASE atomicAdd, tid0-only RELAXED polling (no invalidate per poll),
// single acquire fence per thread on exit. Counters start at the harness's
// 0xAAAAAAAA ws-poison; target = poison + NBLK (unsigned wrap), validated
// by R5's poison-dependent flags passing on every call.
// Residency: __launch_bounds__(512,4) -> <=128 VGPR -> 2 blocks/CU x 256 CU
// = 512 = grid -> all blocks resident -> barrier cannot deadlock.

typedef _Float16 half8 __attribute__((ext_vector_type(8)));
typedef _Float16 half4v __attribute__((ext_vector_type(4)));
typedef float float4v __attribute__((ext_vector_type(4)));

#define NN 4096
#define CC 32
#define L2E 1.44269504f
#define SHIFT 48.0f
#define NBLK 512

__device__ __forceinline__ void gbar(unsigned* __restrict__ cnt, int which) {
    __syncthreads();                       // all waves' stores drained to L2
    if (threadIdx.x == 0) {
        // RELEASE arrival: writes back this block's dirty lines to the
        // coherent point before the arrival becomes visible. One per block.
        __hip_atomic_fetch_add(&cnt[which * 32], 1u, __ATOMIC_RELEASE,
                               __HIP_MEMORY_SCOPE_AGENT);
        // RELAXED single-poller spin: agent-scope atomic load is served from
        // the coherent point (no stale-L2 risk) and emits NO cache
        // invalidate per iteration — this was R5's 170 us/barrier bug.
        while (__hip_atomic_load(&cnt[which * 32], __ATOMIC_RELAXED,
                                 __HIP_MEMORY_SCOPE_AGENT) - 0xAAAAAAAAu
               < (unsigned)NBLK)
            __builtin_amdgcn_s_sleep(1);
    }
    __syncthreads();
    // Single ACQUIRE: invalidate stale cached lines before reading data
    // produced by other blocks.
    __builtin_amdgcn_fence(__ATOMIC_ACQUIRE, "agent");
}

__global__ __launch_bounds__(512, 4) void k_fused(const float* __restrict__ x,
                                                  _Float16* __restrict__ xf,
                                                  _Float16* __restrict__ xt,
                                                  float* __restrict__ c2,
                                                  unsigned* __restrict__ cnt,
                                                  const float* __restrict__ gamma,
                                                  float* __restrict__ out) {
    const int tid = threadIdx.x;
    const int bid = blockIdx.x;
    const int wave = tid >> 6, lane = tid & 63;
    const int quad = lane >> 4, l15 = lane & 15;

    __shared__ float zw[8][16];
    __shared__ _Float16 pt[8][2][16 * 40];   // wave x parity x (16 rows, stride 40)
    __shared__ float red[8][16][32];

    // ---------------- phase 0: convert (blocks 0..127, 65536 threads) ----------------
    if (bid < 128) {
        const int t = bid * 512 + tid;
        const int n  = t & 4095;
        const int cg = (t >> 12) & 7;
        const int b  = t >> 15;
        const int row = (b << 12) | n;
        float4 v = *(const float4*)(x + (size_t)row * CC + cg * 4);
        _Float16 h0 = (_Float16)v.x, h1 = (_Float16)v.y, h2 = (_Float16)v.z, h3 = (_Float16)v.w;
        *(half4v*)(xf + (size_t)row * CC + cg * 4) = (half4v){h0, h1, h2, h3};
        _Float16* xtb = xt + (size_t)b * CC * NN;
        xtb[(cg * 4 + 0) * NN + n] = h0;   // consecutive lanes -> consecutive n
        xtb[(cg * 4 + 1) * NN + n] = h1;
        xtb[(cg * 4 + 2) * NN + n] = h2;
        xtb[(cg * 4 + 3) * NN + n] = h3;
    }

    gbar(cnt, 0);

    // ---------------- phase 1: per-row shifted sum-of-exp -> c2 ----------------
    {
        const int b  = bid >> 8;
        const int i0 = (bid & 255) * 16;
        const _Float16* xb = xf + (size_t)b * NN * CC;

        const half8 afrag = *(const half8*)(xb + (size_t)(i0 + l15) * CC + quad * 8);
        const float4v zf = {0.f, 0.f, 0.f, 0.f};
        float z[4] = {0.f, 0.f, 0.f, 0.f};
        const float c2c = -SHIFT * L2E;

        const int jbase = wave * 512;
        for (int jt = 0; jt < 8; ++jt) {     // 8 iters x 4 tiles x 16 j = 512 j
            const int j0 = jbase + jt * 64;
            half8 b0 = *(const half8*)(xb + (size_t)(j0 + l15) * CC + quad * 8);
            half8 b1 = *(const half8*)(xb + (size_t)(j0 + 16 + l15) * CC + quad * 8);
            half8 b2 = *(const half8*)(xb + (size_t)(j0 + 32 + l15) * CC + quad * 8);
            half8 b3 = *(const half8*)(xb + (size_t)(j0 + 48 + l15) * CC + quad * 8);
            float4v s0 = __builtin_amdgcn_mfma_f32_16x16x32_f16(afrag, b0, zf, 0, 0, 0);
            float4v s1 = __builtin_amdgcn_mfma_f32_16x16x32_f16(afrag, b1, zf, 0, 0, 0);
            float4v s2 = __builtin_amdgcn_mfma_f32_16x16x32_f16(afrag, b2, zf, 0, 0, 0);
            float4v s3 = __builtin_amdgcn_mfma_f32_16x16x32_f16(afrag, b3, zf, 0, 0, 0);
#pragma unroll
            for (int r = 0; r < 4; ++r) {
                z[r] += __builtin_amdgcn_exp2f(fmaf(s0[r], L2E, c2c));
                z[r] += __builtin_amdgcn_exp2f(fmaf(s1[r], L2E, c2c));
                z[r] += __builtin_amdgcn_exp2f(fmaf(s2[r], L2E, c2c));
                z[r] += __builtin_amdgcn_exp2f(fmaf(s3[r], L2E, c2c));
            }
        }
#pragma unroll
        for (int off = 1; off <= 8; off <<= 1) {
#pragma unroll
            for (int r = 0; r < 4; ++r) z[r] += __shfl_xor(z[r], off, 64);
        }
        if (l15 == 0) {
#pragma unroll
            for (int r = 0; r < 4; ++r) zw[wave][quad * 4 + r] = z[r];
        }
        __syncthreads();
        if (tid < 16) {
            float zs = 0.f;
#pragma unroll
            for (int w = 0; w < 8; ++w) zs += zw[w][tid];
            c2[b * NN + i0 + tid] = -(__builtin_amdgcn_logf(zs) + SHIFT * L2E);
        }
    }

    gbar(cnt, 1);

    // ---------------- phase 2: output pass ----------------
    {
        const int b  = bid >> 8;
        const int j0 = (bid & 255) * 16;
        const _Float16* xb  = xf + (size_t)b * NN * CC;
        const _Float16* xtb = xt + (size_t)b * CC * NN;
        const float* c2b = c2 + b * NN;

        const half8 bjfrag = *(const half8*)(xb + (size_t)(j0 + l15) * CC + quad * 8);
        const float4v zf = {0.f, 0.f, 0.f, 0.f};
        float4v acc0 = zf, acc1 = zf;

        const int ibase = wave * 512;
        half8 a0  = *(const half8*)(xb + (size_t)(ibase + l15) * CC + quad * 8);
        half8 a1  = *(const half8*)(xb + (size_t)(ibase + 16 + l15) * CC + quad * 8);
        half8 xb0 = *(const half8*)(xtb + (size_t)l15 * NN + ibase + quad * 8);
        half8 xb1 = *(const half8*)(xtb + (size_t)(l15 + 16) * NN + ibase + quad * 8);
        float4v c20 = *(const float4v*)(c2b + ibase + quad * 4);
        float4v c21 = *(const float4v*)(c2b + ibase + 16 + quad * 4);

        for (int it = 0; it < 16; ++it) {
            const int inx = ibase + ((it + 1) & 15) * 32;
            half8 na0  = *(const half8*)(xb + (size_t)(inx + l15) * CC + quad * 8);
            half8 na1  = *(const half8*)(xb + (size_t)(inx + 16 + l15) * CC + quad * 8);
            half8 nxb0 = *(const half8*)(xtb + (size_t)l15 * NN + inx + quad * 8);
            half8 nxb1 = *(const half8*)(xtb + (size_t)(l15 + 16) * NN + inx + quad * 8);
            float4v nc20 = *(const float4v*)(c2b + inx + quad * 4);
            float4v nc21 = *(const float4v*)(c2b + inx + 16 + quad * 4);

            float4v s0 = __builtin_amdgcn_mfma_f32_16x16x32_f16(a0, bjfrag, zf, 0, 0, 0);
            float4v s1 = __builtin_amdgcn_mfma_f32_16x16x32_f16(a1, bjfrag, zf, 0, 0, 0);
            half4v p0, p1;
#pragma unroll
            for (int r = 0; r < 4; ++r) {
                p0[r] = (_Float16)__builtin_amdgcn_exp2f(fmaf(s0[r], L2E, c20[r]));
                p1[r] = (_Float16)__builtin_amdgcn_exp2f(fmaf(s1[r], L2E, c21[r]));
            }
            _Float16* ptw = &pt[wave][it & 1][0];
            *(half4v*)(ptw + l15 * 40 + quad * 4)      = p0;
            *(half4v*)(ptw + l15 * 40 + 16 + quad * 4) = p1;
            half8 a2 = *(const half8*)(ptw + l15 * 40 + quad * 8);   // P^T[j=l15][i]
            acc0 = __builtin_amdgcn_mfma_f32_16x16x32_f16(a2, xb0, acc0, 0, 0, 0);
            acc1 = __builtin_amdgcn_mfma_f32_16x16x32_f16(a2, xb1, acc1, 0, 0, 0);

            a0 = na0; a1 = na1; xb0 = nxb0; xb1 = nxb1; c20 = nc20; c21 = nc21;
        }

#pragma unroll
        for (int r = 0; r < 4; ++r) {
            red[wave][quad * 4 + r][l15]      = acc0[r];
            red[wave][quad * 4 + r][l15 + 16] = acc1[r];
        }
        __syncthreads();
        {
            const int jj = tid >> 5, c = tid & 31;   // 512 threads = 16 j x 32 c
            float s = 0.f;
#pragma unroll
            for (int w = 0; w < 8; ++w) s += red[w][jj][c];
            const float g = gamma[0];
            const size_t o = (size_t)(b * NN + j0 + jj) * CC + c;
            out[o] = fmaf(g, s, x[o]);
        }
    }
}

extern "C" void kernel_launch(void* const* d_in, const int* in_sizes, int n_in,
                              void* d_out, int out_size, void* d_ws, size_t ws_size,
                              hipStream_t stream) {
    const float* x     = (const float*)d_in[0];
    const float* gamma = (const float*)d_in[1];
    float* out = (float*)d_out;

    // ws layout: xf f16 (512 KB) | xt f16 (512 KB) | c2 fp32 (32 KB) | cnt (256 B)
    _Float16* xf = (_Float16*)d_ws;
    _Float16* xt = xf + (size_t)2 * NN * CC;
    float*    c2 = (float*)(xt + (size_t)2 * CC * NN);
    unsigned* cnt = (unsigned*)(c2 + 2 * NN);

    k_fused<<<dim3(NBLK), dim3(512), 0, stream>>>(x, xf, xt, c2, cnt, gamma, out);
}

// Round 7
// 119.901 us; speedup vs baseline: 3.3428x; 1.9873x over previous
//
#include <hip/hip_runtime.h>

// ChannelAttention b=2, n=4096, c=32 fp32.
// S = X X^T (Gram), softmax over j per row i, out[j,c] = sum_i attn[i,j] x[i,c]; out*g + x.
//
// Single fused dispatch, two device-wide FLUSH-FREE barriers.
// R5: per-thread acquire polling -> buffer_inv storm (358 us).
// R6: release-arrival/acquire-exit barrier -> per-block buffer_wbl2 + wave
//     buffer_inv, ~85 us/barrier (193 us kernel, work only ~15 us).
// R7: no release/acquire at all. All cross-block data (xf, xt, c2) is written
// with SYSTEM-scope RELAXED atomic stores (sc0 sc1: bypass L1+L2, land at the
// coherent point). Barrier = vmcnt drain + relaxed system atomicAdd arrival +
// tid0 relaxed system poll + compiler fence. Consumers' caches never held
// those lines (poison-fill dirt was flushed by the inter-dispatch release
// before kernel start — validated by R5/R6 passing), so no invalidate needed.
// Residency: __launch_bounds__(512,4) -> <=128 VGPR -> 2 blocks/CU x 256 CU
// = grid 512 -> all blocks resident -> no deadlock.
// Counters start at ws-poison 0xAAAAAAAA; target poison+512 (unsigned wrap).

typedef _Float16 half8 __attribute__((ext_vector_type(8)));
typedef _Float16 half4v __attribute__((ext_vector_type(4)));
typedef float float4v __attribute__((ext_vector_type(4)));

#define NN 4096
#define CC 32
#define L2E 1.44269504f
#define SHIFT 48.0f
#define NBLK 512

__device__ __forceinline__ void store_sys_u64(void* p, unsigned long long v) {
    __hip_atomic_store((unsigned long long*)p, v, __ATOMIC_RELAXED,
                       __HIP_MEMORY_SCOPE_SYSTEM);
}

__device__ __forceinline__ void gbar(unsigned* __restrict__ cnt, int which) {
    // all of this wave's sc1 stores acked at the coherent point:
    asm volatile("s_waitcnt vmcnt(0)" ::: "memory");
    __syncthreads();
    if (threadIdx.x == 0) {
        __hip_atomic_fetch_add(&cnt[which * 32], 1u, __ATOMIC_RELAXED,
                               __HIP_MEMORY_SCOPE_SYSTEM);
        while (__hip_atomic_load(&cnt[which * 32], __ATOMIC_RELAXED,
                                 __HIP_MEMORY_SCOPE_SYSTEM) - 0xAAAAAAAAu
               < (unsigned)NBLK)
            __builtin_amdgcn_s_sleep(8);
    }
    __syncthreads();
    __atomic_signal_fence(__ATOMIC_ACQ_REL);   // compiler-only: no hoisting
}

__global__ __launch_bounds__(512, 4) void k_fused(const float* __restrict__ x,
                                                  _Float16* __restrict__ xf,
                                                  _Float16* __restrict__ xt,
                                                  float* __restrict__ c2,
                                                  unsigned* __restrict__ cnt,
                                                  const float* __restrict__ gamma,
                                                  float* __restrict__ out) {
    const int tid = threadIdx.x;
    const int bid = blockIdx.x;
    const int wave = tid >> 6, lane = tid & 63;
    const int quad = lane >> 4, l15 = lane & 15;

    __shared__ float zw[8][16];
    __shared__ _Float16 pt[8][2][16 * 40];   // wave x parity x (16 rows, stride 40)
    __shared__ float red[8][16][32];

    // ---------------- phase 0: convert (blocks 0..255) ----------------
    if (bid < 128) {
        // xf row-major: one half4 group per thread (65536 groups)
        const int t = bid * 512 + tid;
        const int row = t >> 3;            // b*4096 + n
        const int cg  = t & 7;
        float4 v = *(const float4*)(x + (size_t)row * CC + cg * 4);
        half4v h = {(_Float16)v.x, (_Float16)v.y, (_Float16)v.z, (_Float16)v.w};
        store_sys_u64(xf + (size_t)row * CC + cg * 4,
                      __builtin_bit_cast(unsigned long long, h));
    } else if (bid < 256) {
        // xt [b][c][n]: one half4 group over 4 consecutive n per thread
        const int t = (bid - 128) * 512 + tid;
        const int c = t & 31;
        const int g = (t >> 5) & 1023;     // n-group within batch
        const int b = t >> 15;
        const float* xbb = x + (size_t)b * NN * CC;
        const int n0 = g * 4;
        half4v h;
#pragma unroll
        for (int k = 0; k < 4; ++k) h[k] = (_Float16)xbb[(size_t)(n0 + k) * CC + c];
        store_sys_u64(xt + (size_t)b * CC * NN + (size_t)c * NN + n0,
                      __builtin_bit_cast(unsigned long long, h));
    }

    gbar(cnt, 0);

    // ---------------- phase 1: per-row shifted sum-of-exp -> c2 ----------------
    {
        const int b  = bid >> 8;
        const int i0 = (bid & 255) * 16;
        const _Float16* xb = xf + (size_t)b * NN * CC;

        const half8 afrag = *(const half8*)(xb + (size_t)(i0 + l15) * CC + quad * 8);
        const float4v zf = {0.f, 0.f, 0.f, 0.f};
        float z[4] = {0.f, 0.f, 0.f, 0.f};
        const float c2c = -SHIFT * L2E;

        const int jbase = wave * 512;
        for (int jt = 0; jt < 8; ++jt) {     // 8 iters x 4 tiles x 16 j = 512 j
            const int j0 = jbase + jt * 64;
            half8 b0 = *(const half8*)(xb + (size_t)(j0 + l15) * CC + quad * 8);
            half8 b1 = *(const half8*)(xb + (size_t)(j0 + 16 + l15) * CC + quad * 8);
            half8 b2 = *(const half8*)(xb + (size_t)(j0 + 32 + l15) * CC + quad * 8);
            half8 b3 = *(const half8*)(xb + (size_t)(j0 + 48 + l15) * CC + quad * 8);
            float4v s0 = __builtin_amdgcn_mfma_f32_16x16x32_f16(afrag, b0, zf, 0, 0, 0);
            float4v s1 = __builtin_amdgcn_mfma_f32_16x16x32_f16(afrag, b1, zf, 0, 0, 0);
            float4v s2 = __builtin_amdgcn_mfma_f32_16x16x32_f16(afrag, b2, zf, 0, 0, 0);
            float4v s3 = __builtin_amdgcn_mfma_f32_16x16x32_f16(afrag, b3, zf, 0, 0, 0);
#pragma unroll
            for (int r = 0; r < 4; ++r) {
                z[r] += __builtin_amdgcn_exp2f(fmaf(s0[r], L2E, c2c));
                z[r] += __builtin_amdgcn_exp2f(fmaf(s1[r], L2E, c2c));
                z[r] += __builtin_amdgcn_exp2f(fmaf(s2[r], L2E, c2c));
                z[r] += __builtin_amdgcn_exp2f(fmaf(s3[r], L2E, c2c));
            }
        }
#pragma unroll
        for (int off = 1; off <= 8; off <<= 1) {
#pragma unroll
            for (int r = 0; r < 4; ++r) z[r] += __shfl_xor(z[r], off, 64);
        }
        if (l15 == 0) {
#pragma unroll
            for (int r = 0; r < 4; ++r) zw[wave][quad * 4 + r] = z[r];
        }
        __syncthreads();
        if (tid < 16) {
            float zs = 0.f;
#pragma unroll
            for (int w = 0; w < 8; ++w) zs += zw[w][tid];
            float val = -(__builtin_amdgcn_logf(zs) + SHIFT * L2E);
            __hip_atomic_store(&c2[b * NN + i0 + tid], val, __ATOMIC_RELAXED,
                               __HIP_MEMORY_SCOPE_SYSTEM);
        }
    }

    gbar(cnt, 1);

    // ---------------- phase 2: output pass ----------------
    {
        const int b  = bid >> 8;
        const int j0 = (bid & 255) * 16;
        const _Float16* xb  = xf + (size_t)b * NN * CC;
        const _Float16* xtb = xt + (size_t)b * CC * NN;
        const float* c2b = c2 + b * NN;

        const half8 bjfrag = *(const half8*)(xb + (size_t)(j0 + l15) * CC + quad * 8);
        const float4v zf = {0.f, 0.f, 0.f, 0.f};
        float4v acc0 = zf, acc1 = zf;

        const int ibase = wave * 512;
        half8 a0  = *(const half8*)(xb + (size_t)(ibase + l15) * CC + quad * 8);
        half8 a1  = *(const half8*)(xb + (size_t)(ibase + 16 + l15) * CC + quad * 8);
        half8 xb0 = *(const half8*)(xtb + (size_t)l15 * NN + ibase + quad * 8);
        half8 xb1 = *(const half8*)(xtb + (size_t)(l15 + 16) * NN + ibase + quad * 8);
        float4v c20 = *(const float4v*)(c2b + ibase + quad * 4);
        float4v c21 = *(const float4v*)(c2b + ibase + 16 + quad * 4);

        for (int it = 0; it < 16; ++it) {
            const int inx = ibase + ((it + 1) & 15) * 32;
            half8 na0  = *(const half8*)(xb + (size_t)(inx + l15) * CC + quad * 8);
            half8 na1  = *(const half8*)(xb + (size_t)(inx + 16 + l15) * CC + quad * 8);
            half8 nxb0 = *(const half8*)(xtb + (size_t)l15 * NN + inx + quad * 8);
            half8 nxb1 = *(const half8*)(xtb + (size_t)(l15 + 16) * NN + inx + quad * 8);
            float4v nc20 = *(const float4v*)(c2b + inx + quad * 4);
            float4v nc21 = *(const float4v*)(c2b + inx + 16 + quad * 4);

            float4v s0 = __builtin_amdgcn_mfma_f32_16x16x32_f16(a0, bjfrag, zf, 0, 0, 0);
            float4v s1 = __builtin_amdgcn_mfma_f32_16x16x32_f16(a1, bjfrag, zf, 0, 0, 0);
            half4v p0, p1;
#pragma unroll
            for (int r = 0; r < 4; ++r) {
                p0[r] = (_Float16)__builtin_amdgcn_exp2f(fmaf(s0[r], L2E, c20[r]));
                p1[r] = (_Float16)__builtin_amdgcn_exp2f(fmaf(s1[r], L2E, c21[r]));
            }
            _Float16* ptw = &pt[wave][it & 1][0];
            *(half4v*)(ptw + l15 * 40 + quad * 4)      = p0;
            *(half4v*)(ptw + l15 * 40 + 16 + quad * 4) = p1;
            half8 a2 = *(const half8*)(ptw + l15 * 40 + quad * 8);   // P^T[j=l15][i]
            acc0 = __builtin_amdgcn_mfma_f32_16x16x32_f16(a2, xb0, acc0, 0, 0, 0);
            acc1 = __builtin_amdgcn_mfma_f32_16x16x32_f16(a2, xb1, acc1, 0, 0, 0);

            a0 = na0; a1 = na1; xb0 = nxb0; xb1 = nxb1; c20 = nc20; c21 = nc21;
        }

#pragma unroll
        for (int r = 0; r < 4; ++r) {
            red[wave][quad * 4 + r][l15]      = acc0[r];
            red[wave][quad * 4 + r][l15 + 16] = acc1[r];
        }
        __syncthreads();
        {
            const int jj = tid >> 5, c = tid & 31;   // 512 threads = 16 j x 32 c
            float s = 0.f;
#pragma unroll
            for (int w = 0; w < 8; ++w) s += red[w][jj][c];
            const float g = gamma[0];
            const size_t o = (size_t)(b * NN + j0 + jj) * CC + c;
            out[o] = fmaf(g, s, x[o]);
        }
    }
}

extern "C" void kernel_launch(void* const* d_in, const int* in_sizes, int n_in,
                              void* d_out, int out_size, void* d_ws, size_t ws_size,
                              hipStream_t stream) {
    const float* x     = (const float*)d_in[0];
    const float* gamma = (const float*)d_in[1];
    float* out = (float*)d_out;

    // ws layout: xf f16 (512 KB) | xt f16 (512 KB) | c2 fp32 (32 KB) | cnt (256 B)
    _Float16* xf = (_Float16*)d_ws;
    _Float16* xt = xf + (size_t)2 * NN * CC;
    float*    c2 = (float*)(xt + (size_t)2 * CC * NN);
    unsigned* cnt = (unsigned*)(c2 + 2 * NN);

    k_fused<<<dim3(NBLK), dim3(512), 0, stream>>>(x, xf, xt, c2, cnt, gamma, out);
}

// Round 8
// 112.950 us; speedup vs baseline: 3.5486x; 1.0615x over previous
//
#include <hip/hip_runtime.h>

// ChannelAttention b=2, n=4096, c=32 fp32.
// S = X X^T (Gram), softmax over j per row i, out[j,c] = sum_i attn[i,j] x[i,c]; out*g + x.
//
// R5-R7 lesson: software device-wide barriers cost 25-85 us/each on this
// fabric (far-atomic single-line serialization / cache-flush storms), while a
// plain dispatch boundary costs ~10 us (R4 measurement). So: TWO dispatches,
// ZERO in-kernel barriers; cross-dispatch visibility is the HW inter-dispatch
// release/acquire.
//   k_lse: block = 16-i tile. Loads its own fp32 tile, cvt in-register
//          (A-frag), writes its xf/xt f16 tiles for dispatch 2, streams all
//          j-rows from fp32 x (cvt on the fly) -> Z_i -> c2[i]=-(ln Z + 48).
//   k_out: block = 16-j tile. S-MFMA -> exp2(s*log2e + c2[i]) -> per-wave
//          double-buffered LDS C->A relayout -> PV-MFMA with xt -> +residual.
// Layouts (HW-verified): A/B frag = row[lane&15], k = quad*8+t (16B contig);
// C/D: col=lane&15 (B index), row=quad*4+reg (A index).

typedef _Float16 half8 __attribute__((ext_vector_type(8)));
typedef _Float16 half4v __attribute__((ext_vector_type(4)));
typedef float float4v __attribute__((ext_vector_type(4)));

#define NN 4096
#define CC 32
#define L2E 1.44269504f
#define SHIFT 48.0f

__device__ __forceinline__ half8 cvt8(const float* p) {
    float4 v0 = *(const float4*)p;
    float4 v1 = *(const float4*)(p + 4);
    return (half8){(_Float16)v0.x, (_Float16)v0.y, (_Float16)v0.z, (_Float16)v0.w,
                   (_Float16)v1.x, (_Float16)v1.y, (_Float16)v1.z, (_Float16)v1.w};
}

// ---------------- dispatch 1: LSE + f16 tile production ----------------
__global__ __launch_bounds__(512, 4) void k_lse(const float* __restrict__ x,
                                                _Float16* __restrict__ xf,
                                                _Float16* __restrict__ xt,
                                                float* __restrict__ c2) {
    const int tid = threadIdx.x;
    const int wave = tid >> 6, lane = tid & 63;
    const int quad = lane >> 4, l15 = lane & 15;
    const int b  = blockIdx.x >> 8;
    const int i0 = (blockIdx.x & 255) * 16;
    const float* xbb = x + (size_t)b * NN * CC;

    // own i-tile: fp32 -> f16 A-frag (row i0+l15, c = quad*8..+7)
    const half8 afrag = cvt8(xbb + (size_t)(i0 + l15) * CC + quad * 8);

    // produce f16 tiles for dispatch 2 (HW inter-dispatch release makes them visible)
    if (wave == 0) {
        *(half8*)(xf + (size_t)(b * NN + i0 + l15) * CC + quad * 8) = afrag;
    } else if (wave == 1) {
        const int c = lane >> 1, hf = lane & 1;      // 32 c x 2 row-halves
        const int r0 = i0 + hf * 8;
        half8 t;
#pragma unroll
        for (int k = 0; k < 8; ++k) t[k] = (_Float16)xbb[(size_t)(r0 + k) * CC + c];
        *(half8*)(xt + (size_t)b * CC * NN + (size_t)c * NN + r0) = t;
    }

    const float4v zf = {0.f, 0.f, 0.f, 0.f};
    float z[4] = {0.f, 0.f, 0.f, 0.f};
    const float c2c = -SHIFT * L2E;

    const int jbase = wave * 512;
    for (int jt = 0; jt < 8; ++jt) {       // 8 iters x 4 tiles x 16 j = 512 j
        const int j0 = jbase + jt * 64;
        half8 b0 = cvt8(xbb + (size_t)(j0 + l15) * CC + quad * 8);
        half8 b1 = cvt8(xbb + (size_t)(j0 + 16 + l15) * CC + quad * 8);
        half8 b2 = cvt8(xbb + (size_t)(j0 + 32 + l15) * CC + quad * 8);
        half8 b3 = cvt8(xbb + (size_t)(j0 + 48 + l15) * CC + quad * 8);
        float4v s0 = __builtin_amdgcn_mfma_f32_16x16x32_f16(afrag, b0, zf, 0, 0, 0);
        float4v s1 = __builtin_amdgcn_mfma_f32_16x16x32_f16(afrag, b1, zf, 0, 0, 0);
        float4v s2 = __builtin_amdgcn_mfma_f32_16x16x32_f16(afrag, b2, zf, 0, 0, 0);
        float4v s3 = __builtin_amdgcn_mfma_f32_16x16x32_f16(afrag, b3, zf, 0, 0, 0);
#pragma unroll
        for (int r = 0; r < 4; ++r) {
            z[r] += __builtin_amdgcn_exp2f(fmaf(s0[r], L2E, c2c));
            z[r] += __builtin_amdgcn_exp2f(fmaf(s1[r], L2E, c2c));
            z[r] += __builtin_amdgcn_exp2f(fmaf(s2[r], L2E, c2c));
            z[r] += __builtin_amdgcn_exp2f(fmaf(s3[r], L2E, c2c));
        }
    }
    // sum over the 16 j-lanes within each quad group
#pragma unroll
    for (int off = 1; off <= 8; off <<= 1) {
#pragma unroll
        for (int r = 0; r < 4; ++r) z[r] += __shfl_xor(z[r], off, 64);
    }
    __shared__ float zw[8][16];
    if (l15 == 0) {
#pragma unroll
        for (int r = 0; r < 4; ++r) zw[wave][quad * 4 + r] = z[r];
    }
    __syncthreads();
    if (tid < 16) {
        float zs = 0.f;
#pragma unroll
        for (int w = 0; w < 8; ++w) zs += zw[w][tid];
        c2[b * NN + i0 + tid] = -(__builtin_amdgcn_logf(zs) + SHIFT * L2E);
    }
}

// ---------------- dispatch 2: output pass ----------------
__global__ __launch_bounds__(512, 4) void k_out(const _Float16* __restrict__ xf,
                                                const _Float16* __restrict__ xt,
                                                const float* __restrict__ c2,
                                                const float* __restrict__ x,
                                                const float* __restrict__ gamma,
                                                float* __restrict__ out) {
    const int tid = threadIdx.x;
    const int wave = tid >> 6, lane = tid & 63;
    const int quad = lane >> 4, l15 = lane & 15;
    const int b  = blockIdx.x >> 8;
    const int j0 = (blockIdx.x & 255) * 16;
    const _Float16* xb  = xf + (size_t)b * NN * CC;
    const _Float16* xtb = xt + (size_t)b * CC * NN;
    const float* c2b = c2 + b * NN;

    __shared__ _Float16 pt[8][2][16 * 40];   // wave x parity x (16 rows, stride 40)
    __shared__ float red[8][16][32];

    const half8 bjfrag = *(const half8*)(xb + (size_t)(j0 + l15) * CC + quad * 8);
    const float4v zf = {0.f, 0.f, 0.f, 0.f};
    float4v acc0 = zf, acc1 = zf;

    const int ibase = wave * 512;
    half8 a0  = *(const half8*)(xb + (size_t)(ibase + l15) * CC + quad * 8);
    half8 a1  = *(const half8*)(xb + (size_t)(ibase + 16 + l15) * CC + quad * 8);
    half8 xb0 = *(const half8*)(xtb + (size_t)l15 * NN + ibase + quad * 8);
    half8 xb1 = *(const half8*)(xtb + (size_t)(l15 + 16) * NN + ibase + quad * 8);
    float4v c20 = *(const float4v*)(c2b + ibase + quad * 4);
    float4v c21 = *(const float4v*)(c2b + ibase + 16 + quad * 4);

    for (int it = 0; it < 16; ++it) {
        const int inx = ibase + ((it + 1) & 15) * 32;
        half8 na0  = *(const half8*)(xb + (size_t)(inx + l15) * CC + quad * 8);
        half8 na1  = *(const half8*)(xb + (size_t)(inx + 16 + l15) * CC + quad * 8);
        half8 nxb0 = *(const half8*)(xtb + (size_t)l15 * NN + inx + quad * 8);
        half8 nxb1 = *(const half8*)(xtb + (size_t)(l15 + 16) * NN + inx + quad * 8);
        float4v nc20 = *(const float4v*)(c2b + inx + quad * 4);
        float4v nc21 = *(const float4v*)(c2b + inx + 16 + quad * 4);

        float4v s0 = __builtin_amdgcn_mfma_f32_16x16x32_f16(a0, bjfrag, zf, 0, 0, 0);
        float4v s1 = __builtin_amdgcn_mfma_f32_16x16x32_f16(a1, bjfrag, zf, 0, 0, 0);
        half4v p0, p1;
#pragma unroll
        for (int r = 0; r < 4; ++r) {
            p0[r] = (_Float16)__builtin_amdgcn_exp2f(fmaf(s0[r], L2E, c20[r]));
            p1[r] = (_Float16)__builtin_amdgcn_exp2f(fmaf(s1[r], L2E, c21[r]));
        }
        _Float16* ptw = &pt[wave][it & 1][0];
        *(half4v*)(ptw + l15 * 40 + quad * 4)      = p0;
        *(half4v*)(ptw + l15 * 40 + 16 + quad * 4) = p1;
        half8 a2 = *(const half8*)(ptw + l15 * 40 + quad * 8);   // P^T[j=l15][i]
        acc0 = __builtin_amdgcn_mfma_f32_16x16x32_f16(a2, xb0, acc0, 0, 0, 0);
        acc1 = __builtin_amdgcn_mfma_f32_16x16x32_f16(a2, xb1, acc1, 0, 0, 0);

        a0 = na0; a1 = na1; xb0 = nxb0; xb1 = nxb1; c20 = nc20; c21 = nc21;
    }

#pragma unroll
    for (int r = 0; r < 4; ++r) {
        red[wave][quad * 4 + r][l15]      = acc0[r];
        red[wave][quad * 4 + r][l15 + 16] = acc1[r];
    }
    __syncthreads();
    {
        const int jj = tid >> 5, c = tid & 31;   // 512 threads = 16 j x 32 c
        float s = 0.f;
#pragma unroll
        for (int w = 0; w < 8; ++w) s += red[w][jj][c];
        const float g = gamma[0];
        const size_t o = (size_t)(b * NN + j0 + jj) * CC + c;
        out[o] = fmaf(g, s, x[o]);
    }
}

extern "C" void kernel_launch(void* const* d_in, const int* in_sizes, int n_in,
                              void* d_out, int out_size, void* d_ws, size_t ws_size,
                              hipStream_t stream) {
    const float* x     = (const float*)d_in[0];
    const float* gamma = (const float*)d_in[1];
    float* out = (float*)d_out;

    // ws layout: xf f16 (512 KB) | xt f16 (512 KB) | c2 fp32 (32 KB)
    _Float16* xf = (_Float16*)d_ws;
    _Float16* xt = xf + (size_t)2 * NN * CC;
    float*    c2 = (float*)(xt + (size_t)2 * CC * NN);

    k_lse<<<dim3(512), dim3(512), 0, stream>>>(x, xf, xt, c2);
    k_out<<<dim3(512), dim3(512), 0, stream>>>(xf, xt, c2, x, gamma, out);
}